// Round 10
// baseline (120.644 us; speedup 1.0000x reference)
//
#include <hip/hip_runtime.h>
#include <stdint.h>

// RandomSelfAttention: B=2, S=4096, S2=2048, NH=8, H=64, NKEYS=64
// q:(B,S2,NH,H) f32, k/v:(B,S,NH,H) f32, idx:(B,S2,NKEYS) int
// out z:(B,S2,NH,H) f32
//
// MODEL (r2-r9 fit): dur tracks gather-line count at ~0.5 lines/cyc/CU.
// fp16 prepass (r9) halved lines: 60us -> ~38us main. Residual gap to the
// ~28us line floor = scalar cvt+fma VALU (~680 cyc/wave > 530 mem cyc).
// THIS ROUND: packed fp16 math. Phase1 v_dot2_f32_f16 (fdot2), phase2
// v_pk_fma_f16 accumulation (f16 sums, f32 only for cross-lane reduce).
// VALU/wave ~340 -> ~170 ops.
//
// Lessons pinned: r3 = never cap regs to 64 (750MB scratch spill);
// r5/r6/r7 = compiler refuses >4-load register batches (don't fight it);
// r8 = 32KB LDS/block chokes occupancy (stay LDS-free).
// Watch WRITE_SIZE (8MB = clean) for spills on any edit.
// Block swizzle: blockIdx%16 = (b,n) combo -> per-XCD L2 set ~2MB (fp16).

#define BB 2
#define SS 4096
#define S2V 2048
#define NHV 8
#define HV 64
#define NKV 64

typedef _Float16 half_t;
typedef _Float16 half8 __attribute__((ext_vector_type(8)));
typedef _Float16 half2t __attribute__((ext_vector_type(2)));

#define NE ((size_t)BB * SS * NHV * HV)   // 4,194,304 elements in k (and v)

// ---- prepass: k,v fp32 -> fp16 into workspace (coalesced stream) ----
__global__ __launch_bounds__(256)
void cvt_kernel(const float* __restrict__ k, const float* __restrict__ v,
                half_t* __restrict__ kh, half_t* __restrict__ vh) {
    const size_t base = ((size_t)blockIdx.x * 256 + threadIdx.x) * 8;
    const float* src; half_t* dst; size_t off;
    if (base < NE) { src = k; dst = kh; off = base; }
    else           { src = v; dst = vh; off = base - NE; }
    const float4 a = *(const float4*)(src + off);
    const float4 b = *(const float4*)(src + off + 4);
    half8 h = { (_Float16)a.x, (_Float16)a.y, (_Float16)a.z, (_Float16)a.w,
                (_Float16)b.x, (_Float16)b.y, (_Float16)b.z, (_Float16)b.w };
    *(half8*)(dst + off) = h;
}

// ---- main: fp16 gather + packed math. Lane = (g=lane>>3, hc=lane&7) ----
__global__ __launch_bounds__(256)
void rsa_fp16_kernel(const float* __restrict__ q, const half_t* __restrict__ kh,
                     const half_t* __restrict__ vh, const int* __restrict__ idx,
                     float* __restrict__ out) {
    const int lane = threadIdx.x & 63;
    const int w    = threadIdx.x >> 6;
    const int bi   = blockIdx.x;

    const int combo = bi & 15;
    const int b     = combo >> 3;
    const int n     = combo & 7;
    const int qi    = ((bi >> 4) << 2) + w;

    const int g  = lane >> 3;    // key group 0..7
    const int hc = lane & 7;     // h-chunk 0..7 (half8 = 16B granularity)

    const size_t bq = (size_t)b * S2V + qi;

    // q chunk: 8 floats, prescaled by h^-0.5 = 1/8, converted to half8 once
    const float* qrow = q + (bq * NHV + n) * HV;
    const float4 qa = *(const float4*)(qrow + hc * 8);
    const float4 qb = *(const float4*)(qrow + hc * 8 + 4);
    const half8 qh = { (_Float16)(qa.x * 0.125f), (_Float16)(qa.y * 0.125f),
                       (_Float16)(qa.z * 0.125f), (_Float16)(qa.w * 0.125f),
                       (_Float16)(qb.x * 0.125f), (_Float16)(qb.y * 0.125f),
                       (_Float16)(qb.z * 0.125f), (_Float16)(qb.w * 0.125f) };

    const int my_off = idx[bq * NKV + lane] * (NHV * HV);

    const half_t* kb = kh + ((size_t)b * SS * NHV + n) * HV;
    const half_t* vb = vh + ((size_t)b * SS * NHV + n) * HV;

    // ---- phase 1: scores via v_dot2_f32_f16. iter it = keys it*8+g ----
    float sc[8];
#pragma unroll
    for (int it = 0; it < 8; ++it) {
        const int off = __shfl(my_off, it * 8 + g, 64);
        const half8 kk = *(const half8*)(kb + off + hc * 8);
        float d = 0.f;
#if __has_builtin(__builtin_amdgcn_fdot2)
        const half2t* k2 = (const half2t*)&kk;
        const half2t* q2 = (const half2t*)&qh;
#pragma unroll
        for (int j = 0; j < 4; ++j)
            d = __builtin_amdgcn_fdot2(k2[j], q2[j], d, false);
#else
#pragma unroll
        for (int j = 0; j < 8; ++j) d = fmaf((float)kk[j], (float)qh[j], d);
#endif
        d += __shfl_xor(d, 1);
        d += __shfl_xor(d, 2);
        d += __shfl_xor(d, 4);
        sc[it] = d;   // full dot of key it*8+g, replicated over 8-lane group
    }

    // ---- softmax over 64 keys ----
    float m = sc[0];
#pragma unroll
    for (int it = 1; it < 8; ++it) m = fmaxf(m, sc[it]);
    m = fmaxf(m, __shfl_xor(m, 8));
    m = fmaxf(m, __shfl_xor(m, 16));
    m = fmaxf(m, __shfl_xor(m, 32));

    float ssum = 0.f;
#pragma unroll
    for (int it = 0; it < 8; ++it) {
        sc[it] = __expf(sc[it] - m);
        ssum += sc[it];
    }
    ssum += __shfl_xor(ssum, 8);
    ssum += __shfl_xor(ssum, 16);
    ssum += __shfl_xor(ssum, 32);
    const float rs = __frcp_rn(ssum);

    // ---- phase 2: packed f16 accumulate (v_pk_fma_f16) ----
    half8 za8 = { (_Float16)0, (_Float16)0, (_Float16)0, (_Float16)0,
                  (_Float16)0, (_Float16)0, (_Float16)0, (_Float16)0 };
#pragma unroll
    for (int it = 0; it < 8; ++it) {
        const int off = __shfl(my_off, it * 8 + g, 64);
        const half8 vv = *(const half8*)(vb + off + hc * 8);
        const _Float16 ph = (_Float16)sc[it];
        za8 += vv * ph;   // 4x v_pk_fma_f16
    }
    // cross-group reduce in f32 (8 partial groups)
    float zf[8];
#pragma unroll
    for (int j = 0; j < 8; ++j) {
        float t = (float)za8[j];
        t += __shfl_xor(t, 8);
        t += __shfl_xor(t, 16);
        t += __shfl_xor(t, 32);
        zf[j] = t;
    }

    if (g == 0) {
        float* orow = out + (bq * NHV + n) * HV + hc * 8;
        float4 o1 = make_float4(zf[0] * rs, zf[1] * rs, zf[2] * rs, zf[3] * rs);
        float4 o2 = make_float4(zf[4] * rs, zf[5] * rs, zf[6] * rs, zf[7] * rs);
        *(float4*)(orow)     = o1;
        *(float4*)(orow + 4) = o2;
    }
}

// ---- fallback (proven round-6 fp32 path) if ws too small ----
__global__ __launch_bounds__(256)
void rsa_fp32_kernel(const float* __restrict__ q, const float* __restrict__ k,
                     const float* __restrict__ v, const int* __restrict__ idx,
                     float* __restrict__ out) {
    const int lane = threadIdx.x & 63;
    const int w    = threadIdx.x >> 6;
    const int bi   = blockIdx.x;
    const int combo = bi & 15;
    const int b     = combo >> 3;
    const int n     = combo & 7;
    const int qi    = ((bi >> 4) << 2) + w;
    const int g  = lane >> 4;
    const int hc = lane & 15;
    const size_t bq = (size_t)b * S2V + qi;
    const float* qrow = q + (bq * NHV + n) * HV;
    const float4 qv = *(const float4*)(qrow + hc * 4);
    const float4 q4 = make_float4(qv.x * 0.125f, qv.y * 0.125f,
                                  qv.z * 0.125f, qv.w * 0.125f);
    const int my_off = idx[bq * NKV + lane] * (NHV * HV);
    const float* kb = k + ((size_t)b * SS * NHV + n) * HV;
    const float* vb = v + ((size_t)b * SS * NHV + n) * HV;
    float sc[16];
#pragma unroll
    for (int it = 0; it < 16; ++it) {
        const int off = __shfl(my_off, it * 4 + g, 64);
        const float4 k4 = *(const float4*)(kb + off + hc * 4);
        float d = k4.x * q4.x + k4.y * q4.y + k4.z * q4.z + k4.w * q4.w;
        d += __shfl_xor(d, 1);
        d += __shfl_xor(d, 2);
        d += __shfl_xor(d, 4);
        d += __shfl_xor(d, 8);
        sc[it] = d;
    }
    float m = sc[0];
#pragma unroll
    for (int it = 1; it < 16; ++it) m = fmaxf(m, sc[it]);
    m = fmaxf(m, __shfl_xor(m, 16));
    m = fmaxf(m, __shfl_xor(m, 32));
    float ssum = 0.f;
#pragma unroll
    for (int it = 0; it < 16; ++it) { sc[it] = __expf(sc[it] - m); ssum += sc[it]; }
    ssum += __shfl_xor(ssum, 16);
    ssum += __shfl_xor(ssum, 32);
    const float rs = __frcp_rn(ssum);
    float4 z = make_float4(0.f, 0.f, 0.f, 0.f);
#pragma unroll
    for (int it = 0; it < 16; ++it) {
        const int off = __shfl(my_off, it * 4 + g, 64);
        const float4 v4 = *(const float4*)(vb + off + hc * 4);
        const float p = sc[it];
        z.x = fmaf(p, v4.x, z.x); z.y = fmaf(p, v4.y, z.y);
        z.z = fmaf(p, v4.z, z.z); z.w = fmaf(p, v4.w, z.w);
    }
    z.x += __shfl_xor(z.x, 16); z.y += __shfl_xor(z.y, 16);
    z.z += __shfl_xor(z.z, 16); z.w += __shfl_xor(z.w, 16);
    z.x += __shfl_xor(z.x, 32); z.y += __shfl_xor(z.y, 32);
    z.z += __shfl_xor(z.z, 32); z.w += __shfl_xor(z.w, 32);
    if (g == 0) {
        float4 zo = make_float4(z.x * rs, z.y * rs, z.z * rs, z.w * rs);
        *(float4*)(out + (bq * NHV + n) * HV + hc * 4) = zo;
    }
}

extern "C" void kernel_launch(void* const* d_in, const int* in_sizes, int n_in,
                              void* d_out, int out_size, void* d_ws, size_t ws_size,
                              hipStream_t stream) {
    const float* q   = (const float*)d_in[0];
    const float* k   = (const float*)d_in[1];
    const float* v   = (const float*)d_in[2];
    const int*   idx = (const int*)d_in[3];
    float*       out = (float*)d_out;

    const int n_units = BB * S2V * NHV;       // 32768 waves
    const int blocks  = n_units / 4;          // 8192 blocks of 4 waves

    const size_t need = 2 * NE * sizeof(half_t);   // 16.8 MB
    if (ws_size >= need) {
        half_t* kh = (half_t*)d_ws;
        half_t* vh = kh + NE;
        const int cvt_blocks = (int)(2 * NE / 8 / 256);   // 4096
        cvt_kernel<<<cvt_blocks, 256, 0, stream>>>(k, v, kh, vh);
        rsa_fp16_kernel<<<blocks, 256, 0, stream>>>(q, kh, vh, idx, out);
    } else {
        rsa_fp32_kernel<<<blocks, 256, 0, stream>>>(q, k, v, idx, out);
    }
}